// Round 2
// baseline (927.378 us; speedup 1.0000x reference)
//
#include <hip/hip_runtime.h>

// B=8, C=64, D=8 (q/k), H=W=128.  dwconv3x3 -> CCA -> CCA -> pointwise.
// Flash-style CCA: never materialize the 256-wide attention.
//  - stats over col scores (on AT) and row scores (on A), combined into M, 1/S
//  - fused out kernels recompute scores, apply exp(e-M)/S, matmul with v
// Col pass == row pass on transposed tensors; ccout col pass writes its own
// AT slice in place (slice fully staged to LDS first), so no extra buffer.
// Workspace: 3x 32MB (y, z, AT) + 6x 512KB stats = 99 MB.

#define NEGINF -3.0e38f

__global__ __launch_bounds__(128) void dwconv_kernel(
    const float* __restrict__ x, const float* __restrict__ wdw, float* __restrict__ y) {
  int w = threadIdx.x;
  int h = blockIdx.x;
  int c = blockIdx.y;
  int b = blockIdx.z;
  const float* xp = x + (((size_t)b*64 + c)*128)*128;
  const float* wp = wdw + c*9;
  float acc = 0.f;
  #pragma unroll
  for (int kh = 0; kh < 3; ++kh) {
    int hh = h + kh - 1;
    if (hh < 0 || hh >= 128) continue;
    #pragma unroll
    for (int kw = 0; kw < 3; ++kw) {
      int ww = w + kw - 1;
      if (ww < 0 || ww >= 128) continue;
      acc += wp[kh*3 + kw] * xp[hh*128 + ww];
    }
  }
  y[(((size_t)b*64 + c)*128 + h)*128 + w] = acc;
}

// Batched 128x128 transpose: 32x32 LDS tiles, coalesced both sides.
__global__ __launch_bounds__(256) void transpose128(
    const float* __restrict__ in, float* __restrict__ out) {
  __shared__ float tile[32][33];
  int n = blockIdx.z;
  int x0 = blockIdx.x*32, y0 = blockIdx.y*32;
  const float* ip = in + (size_t)n*16384;
  float* op = out + (size_t)n*16384;
  for (int i = threadIdx.y; i < 32; i += 8)
    tile[i][threadIdx.x] = ip[(size_t)(y0 + i)*128 + x0 + threadIdx.x];
  __syncthreads();
  for (int i = threadIdx.y; i < 32; i += 8)
    op[(size_t)(x0 + i)*128 + y0 + threadIdx.x] = tile[threadIdx.x][i];
}

// Per (b,r) slice src[((b*64+c)*128+r)*128+p]: on-the-fly q,k projection, then
// per-pixel-p running max & sumexp over the 128 scores e(p,g)=q(p)·k(g).
// mask=1: skip g==p (diagonal, column pass). Writes m,s at ((b*128+r)*128+p).
__global__ __launch_bounds__(128) void stats_kernel(
    const float* __restrict__ src, const float* __restrict__ wq,
    const float* __restrict__ wk, float* __restrict__ mOut,
    float* __restrict__ sOut, int mask) {
  __shared__ float ys[64][129];
  __shared__ float ks[8][128];
  int p = threadIdx.x;
  int r = blockIdx.x, b = blockIdx.y;
  const float* sp = src + (size_t)b*1048576 + (size_t)r*128;
  for (int c = 0; c < 64; ++c) ys[c][p] = sp[(size_t)c*16384 + p];
  __syncthreads();
  float q[8] = {}, k[8] = {};
  for (int c = 0; c < 64; ++c) {
    float yv = ys[c][p];
    #pragma unroll
    for (int d = 0; d < 8; ++d) {
      q[d] += wq[d*64 + c]*yv;   // uniform index -> scalar loads
      k[d] += wk[d*64 + c]*yv;
    }
  }
  #pragma unroll
  for (int d = 0; d < 8; ++d) ks[d][p] = k[d];
  __syncthreads();
  float m = NEGINF;
  for (int g = 0; g < 128; ++g) {
    float e = 0.f;
    #pragma unroll
    for (int d = 0; d < 8; ++d) e += q[d]*ks[d][g];
    if (mask && g == p) e = NEGINF;
    m = fmaxf(m, e);
  }
  float s = 0.f;
  for (int g = 0; g < 128; ++g) {
    float e = 0.f;
    #pragma unroll
    for (int d = 0; d < 8; ++d) e += q[d]*ks[d][g];
    if (!(mask && g == p)) s += __expf(e - m);
  }
  size_t o = ((size_t)b*128 + r)*128 + p;
  mOut[o] = m;
  sOut[o] = s;
}

// Merge row stats (b,h,w) with col stats (b,w,h) -> final M and 1/S at (b,h,w).
__global__ __launch_bounds__(128) void finalize_kernel(
    const float* __restrict__ mW, const float* __restrict__ sW,
    const float* __restrict__ mH, const float* __restrict__ sH,
    float* __restrict__ Mf, float* __restrict__ Sinv) {
  int w = threadIdx.x;
  int h = blockIdx.x, b = blockIdx.y;
  size_t iRow = ((size_t)b*128 + h)*128 + w;
  size_t iCol = ((size_t)b*128 + w)*128 + h;
  float mw = mW[iRow], sw = sW[iRow];
  float mh = mH[iCol], sh = sH[iCol];
  float M = fmaxf(mw, mh);
  float S = sw*__expf(mw - M) + sh*__expf(mh - M);
  Mf[iRow] = M;
  Sinv[iRow] = 1.0f / S;
}

// Fused attention-output for one direction. Block (r,b), 256 threads.
// Slice src[((b*64+c)*128+r)*128+p]; q,k,v projected on the fly; per pixel p:
//   out[d][p] = sum_c exp(e(p,c)-M[pix])*Sinv[pix]*v[d][c], mask skips c==p.
// Pixel index: row pass (mask=0): (b, r, p); col pass (mask=1): (b, p, r).
// dst slice may alias src (col pass writes AT in place).
__global__ __launch_bounds__(256) void ccout_kernel(
    const float* src,
    const float* __restrict__ wq, const float* __restrict__ wk,
    const float* __restrict__ wv,
    const float* __restrict__ Mf, const float* __restrict__ Sinv,
    float* dst, int mask) {
  __shared__ float ys[64][129];   // staged slice, later overwritten with v
  __shared__ float qs[8][128];
  __shared__ float ks[8][128];
  __shared__ float pS[32][129];   // wv staging -> prob chunk -> out staging
  __shared__ float MfS[128], SiS[128];
  int t = threadIdx.x;
  int r = blockIdx.x, b = blockIdx.y;
  const float* sp = src + (size_t)b*1048576 + (size_t)r*128;
  float* wvS = &pS[0][0];         // 4096 floats <= 32*129
  for (int i = t; i < 8192; i += 256) {
    int c = i >> 7, p = i & 127;
    ys[c][p] = sp[(size_t)c*16384 + p];
  }
  for (int i = t; i < 4096; i += 256) wvS[i] = wv[i];
  if (t < 128) {
    size_t pix = mask ? (((size_t)b*128 + t)*128 + r)
                      : (((size_t)b*128 + r)*128 + t);
    MfS[t] = Mf[pix];
    SiS[t] = Sinv[pix];
  }
  __syncthreads();
  int w = t & 127, dbase = (t >> 7)*32;
  float vreg[32] = {};
  if (t < 128) {
    float q[8] = {}, k[8] = {};
    for (int c = 0; c < 64; ++c) {
      float yv = ys[c][t];
      #pragma unroll
      for (int d = 0; d < 8; ++d) { q[d] += wq[d*64+c]*yv; k[d] += wk[d*64+c]*yv; }
    }
    #pragma unroll
    for (int d = 0; d < 8; ++d) { qs[d][t] = q[d]; ks[d][t] = k[d]; }
  }
  for (int c = 0; c < 64; ++c) {
    float yv = ys[c][w];
    #pragma unroll
    for (int j = 0; j < 32; ++j) vreg[j] += wvS[(dbase + j)*64 + c]*yv;
  }
  __syncthreads();                 // all ys/wvS reads done; qs/ks written
  #pragma unroll
  for (int j = 0; j < 32; ++j) ys[dbase + j][w] = vreg[j];   // ys becomes v
  int dl = t & 15, pg = t >> 4;
  float* dp = dst + (size_t)b*1048576 + (size_t)r*128;
  for (int chunk = 0; chunk < 4; ++chunk) {
    int p0 = chunk*32;
    __syncthreads();               // v ready (iter0) / prev out-copy done
    for (int i = t; i < 4096; i += 256) {
      int p = i >> 7, c = i & 127;
      int pa = p0 + p;
      float e = 0.f;
      #pragma unroll
      for (int d = 0; d < 8; ++d) e += qs[d][pa]*ks[d][c];
      pS[p][c] = (mask && c == pa) ? 0.f : __expf(e - MfS[pa])*SiS[pa];
    }
    __syncthreads();
    float acc[4][2] = {{0.f,0.f},{0.f,0.f},{0.f,0.f},{0.f,0.f}};
    for (int c = 0; c < 128; ++c) {
      float a0 = pS[pg][c], a1 = pS[pg+16][c];
      float v0 = ys[dl][c],      v1 = ys[dl+16][c];
      float v2 = ys[dl+32][c],   v3 = ys[dl+48][c];
      acc[0][0] += v0*a0; acc[0][1] += v0*a1;
      acc[1][0] += v1*a0; acc[1][1] += v1*a1;
      acc[2][0] += v2*a0; acc[2][1] += v2*a1;
      acc[3][0] += v3*a0; acc[3][1] += v3*a1;
    }
    __syncthreads();               // pS reads done; reuse as outS
    float* outS = &pS[0][0];       // 64*33 = 2112 <= 4128
    #pragma unroll
    for (int i2 = 0; i2 < 4; ++i2)
      #pragma unroll
      for (int j = 0; j < 2; ++j)
        outS[(dl + 16*i2)*33 + pg + 16*j] = acc[i2][j];
    __syncthreads();
    for (int i = t; i < 2048; i += 256) {
      int d = i >> 5, p = i & 31;
      dp[(size_t)d*16384 + p0 + p] = outS[d*33 + p];
    }
  }
}

// Bo[b,d,h,w] = gamma*(Bo + oT[b,d,w,h]) + A[b,d,h,w], transpose-tile on oT.
__global__ __launch_bounds__(256) void combineT_kernel(
    float* __restrict__ Bo, const float* __restrict__ oT,
    const float* __restrict__ A, const float* __restrict__ gamma) {
  __shared__ float tile[32][33];
  int n = blockIdx.z;                       // b*64 + d
  int x0 = blockIdx.x*32, y0 = blockIdx.y*32;
  const float* ip = oT + (size_t)n*16384;
  for (int i = threadIdx.y; i < 32; i += 8)
    tile[i][threadIdx.x] = ip[(size_t)(y0 + i)*128 + x0 + threadIdx.x]; // [w=y0+i][h=x0+tx]
  __syncthreads();
  float g = *gamma;
  for (int i = threadIdx.y; i < 32; i += 8) {
    size_t idx = (size_t)n*16384 + (size_t)(x0 + i)*128 + (y0 + threadIdx.x); // h=x0+i, w=y0+tx
    float oh = tile[threadIdx.x][i];
    Bo[idx] = g*(Bo[idx] + oh) + A[idx];
  }
}

// Pointwise 64->64 per (b,h) row.
__global__ __launch_bounds__(128) void pw_kernel(
    const float* __restrict__ A, const float* __restrict__ wpw, float* __restrict__ out) {
  __shared__ float ys[64][128];
  int w = threadIdx.x, h = blockIdx.x, b = blockIdx.y;
  for (int c = 0; c < 64; ++c)
    ys[c][w] = A[(((size_t)b*64 + c)*128 + h)*128 + w];
  __syncthreads();
  float acc[64] = {};
  for (int c0 = 0; c0 < 64; c0 += 8) {
    float yreg[8];
    #pragma unroll
    for (int cc = 0; cc < 8; ++cc) yreg[cc] = ys[c0 + cc][w];
    #pragma unroll
    for (int cc = 0; cc < 8; ++cc) {
      #pragma unroll
      for (int o = 0; o < 64; ++o)
        acc[o] += wpw[o*64 + c0 + cc] * yreg[cc];
    }
  }
  #pragma unroll
  for (int o = 0; o < 64; ++o)
    out[(((size_t)b*64 + o)*128 + h)*128 + w] = acc[o];
}

extern "C" void kernel_launch(void* const* d_in, const int* in_sizes, int n_in,
                              void* d_out, int out_size, void* d_ws, size_t ws_size,
                              hipStream_t stream) {
  const float* x     = (const float*)d_in[0];
  const float* wdw   = (const float*)d_in[1];
  const float* wq    = (const float*)d_in[2];
  const float* wk    = (const float*)d_in[3];
  const float* wv    = (const float*)d_in[4];
  const float* gamma = (const float*)d_in[5];
  const float* wpw   = (const float*)d_in[6];
  float* out = (float*)d_out;

  // Workspace layout (floats): 3*8388608 + 6*131072 = 25,952,256 fl = 99 MB
  float* ws = (float*)d_ws;
  float* y  = ws;                 // dwconv out / CCA1 in / CCA2 out
  float* z  = y  + 8388608;       // CCA1 out / CCA2 in
  float* AT = z  + 8388608;       // transposed input, then oH^T (in-place)
  float* mA = AT + 8388608;       // col stats (b,w,h)
  float* sA = mA + 131072;
  float* mB = sA + 131072;        // row stats (b,h,w)
  float* sB = mB + 131072;
  float* Mf = sB + 131072;        // final max (b,h,w)
  float* Si = Mf + 131072;        // final 1/S (b,h,w)
  size_t need = (size_t)25952256 * sizeof(float);
  if (ws_size < need) return;     // clean fail (absmax=ref max) instead of fault

  dwconv_kernel<<<dim3(128, 64, 8), 128, 0, stream>>>(x, wdw, y);

  for (int pass = 0; pass < 2; ++pass) {
    const float* A = pass ? z : y;   // CCA input / residual
    float* Bo      = pass ? y : z;   // CCA output

    transpose128<<<dim3(4, 4, 512), dim3(32, 8), 0, stream>>>(A, AT);
    stats_kernel<<<dim3(128, 8), 128, 0, stream>>>(AT, wq, wk, mA, sA, 1);
    stats_kernel<<<dim3(128, 8), 128, 0, stream>>>(A,  wq, wk, mB, sB, 0);
    finalize_kernel<<<dim3(128, 8), 128, 0, stream>>>(mB, sB, mA, sA, Mf, Si);
    ccout_kernel<<<dim3(128, 8), 256, 0, stream>>>(A,  wq, wk, wv, Mf, Si, Bo, 0);
    ccout_kernel<<<dim3(128, 8), 256, 0, stream>>>(AT, wq, wk, wv, Mf, Si, AT, 1);
    combineT_kernel<<<dim3(4, 4, 512), dim3(32, 8), 0, stream>>>(Bo, AT, A, gamma);
  }

  pw_kernel<<<dim3(128, 8), 128, 0, stream>>>(y, wpw, out);
}

// Round 3
// 381.126 us; speedup vs baseline: 2.4333x; 2.4333x over previous
//
#include <hip/hip_runtime.h>

// B=8, C=64, D=8 (q/k), H=W=128.  dwconv3x3 -> CCA -> CCA -> pointwise.
// MFMA-based flash CCA: per (b,r,dir) block stage slice bf16 in LDS, project
// q/k/v via MFMA, scores E=Q^T K via MFMA (K=8 in quad-0 lanes, other quads
// zero), per-row max/sumexp via shuffle (stats -> global, normalization
// deferred), P=exp(E-m) bf16 -> LDS, O = V x P^T via MFMA (unnormalized).
// scale_kernel merges row/col stats into per-pixel factors cW,cH;
// combineT applies  Bo = gamma*(OW*cW + OH^T*cH) + A.
// Fragment layouts (mfma_f32_16x16x32_bf16):
//   A[m=lane&15][k=quad*8+j], B[k=quad*8+j][n=lane&15], C col=lane&15,row=quad*4+reg

#define NEGINF -3.0e38f
#define YSTR 72
#define VSTR 136
#define PSTR 136

typedef __attribute__((ext_vector_type(8))) __bf16 bf8;
typedef __attribute__((ext_vector_type(4))) float f4;

__device__ __forceinline__ f4 MFMA(bf8 a, bf8 b, f4 c) {
  return __builtin_amdgcn_mfma_f32_16x16x32_bf16(a, b, c, 0, 0, 0);
}

__global__ __launch_bounds__(128) void dwconv_kernel(
    const float* __restrict__ x, const float* __restrict__ wdw, float* __restrict__ y) {
  int w = threadIdx.x;
  int h = blockIdx.x;
  int c = blockIdx.y;
  int b = blockIdx.z;
  const float* xp = x + (((size_t)b*64 + c)*128)*128;
  const float* wp = wdw + c*9;
  float acc = 0.f;
  #pragma unroll
  for (int kh = 0; kh < 3; ++kh) {
    int hh = h + kh - 1;
    if (hh < 0 || hh >= 128) continue;
    #pragma unroll
    for (int kw = 0; kw < 3; ++kw) {
      int ww = w + kw - 1;
      if (ww < 0 || ww >= 128) continue;
      acc += wp[kh*3 + kw] * xp[hh*128 + ww];
    }
  }
  y[(((size_t)b*64 + c)*128 + h)*128 + w] = acc;
}

// Batched 128x128 transpose: 32x32 LDS tiles, coalesced both sides.
__global__ __launch_bounds__(256) void transpose128(
    const float* __restrict__ in, float* __restrict__ out) {
  __shared__ float tile[32][33];
  int n = blockIdx.z;
  int x0 = blockIdx.x*32, y0 = blockIdx.y*32;
  const float* ip = in + (size_t)n*16384;
  float* op = out + (size_t)n*16384;
  for (int i = threadIdx.y; i < 32; i += 8)
    tile[i][threadIdx.x] = ip[(size_t)(y0 + i)*128 + x0 + threadIdx.x];
  __syncthreads();
  for (int i = threadIdx.y; i < 32; i += 8)
    op[(size_t)(x0 + i)*128 + y0 + threadIdx.x] = tile[threadIdx.x][i];
}

// Fused CCA direction kernel. dir=0: src=A row pass -> dstRow, stats mW,sW.
// dir=1: src=dst=AT (in place), diag mask, stats mH,sH.
// Output O is UNNORMALIZED: O[d][p] = sum_c exp(e(p,c)-m[p]) * v[d][c].
__global__ __launch_bounds__(256) void ccdir_kernel(
    const float* __restrict__ srcRow, float* __restrict__ dstRow,
    float* __restrict__ srcdstCol,
    const float* __restrict__ wq, const float* __restrict__ wk,
    const float* __restrict__ wv,
    float* __restrict__ mW, float* __restrict__ sW,
    float* __restrict__ mH, float* __restrict__ sH) {
  // LDS layout (bytes): vs [64][136]bf16 @0 (17408); ps [128][136]bf16 @17408
  // (34816, rows p; per-wave 32-row block = 8704 B reused as fp32 out-stage);
  // ys [128][72]bf16 @17408 (aliases ps, dead after phase 1);
  // qs [128][8]bf16 @35840; ks [128][8]bf16 @37888.  Total 52224.
  __shared__ __align__(16) char smem[52224];
  __bf16* vs = (__bf16*)smem;
  __bf16* ps = (__bf16*)(smem + 17408);
  __bf16* ys = (__bf16*)(smem + 17408);
  __bf16* qs = (__bf16*)(smem + 35840);
  __bf16* ks = (__bf16*)(smem + 37888);

  int t = threadIdx.x;
  int r = blockIdx.x, b = blockIdx.y, dir = blockIdx.z;
  const float* src = dir ? srcdstCol : srcRow;
  float* dst       = dir ? srcdstCol : dstRow;
  float* mo        = dir ? mH : mW;
  float* so        = dir ? sH : sW;
  const float* sp = src + (size_t)b*1048576 + (size_t)r*128;

  // ---- phase 0: stage Y[c][p] -> ys[p][c] bf16; load weight A-frags ----
  for (int i = t; i < 8192; i += 256) {
    int c = i >> 7, p = i & 127;
    ys[p*YSTR + c] = (__bf16)sp[(size_t)c*16384 + p];
  }
  int lane = t & 63, w = t >> 6;
  int l16 = lane & 15, quad = lane >> 4;

  bf8 a_qk[2], a_wv[4][2];
  {
    const float* wr = (l16 < 8) ? (wq + l16*64) : (wk + (l16 - 8)*64);
    #pragma unroll
    for (int s = 0; s < 2; ++s) {
      int c0 = quad*8 + s*32;
      bf8 f;
      #pragma unroll
      for (int j = 0; j < 8; ++j) f[j] = (__bf16)wr[c0 + j];
      a_qk[s] = f;
    }
    #pragma unroll
    for (int m0 = 0; m0 < 4; ++m0) {
      const float* vr = wv + (m0*16 + l16)*64;
      #pragma unroll
      for (int s = 0; s < 2; ++s) {
        int c0 = quad*8 + s*32;
        bf8 f;
        #pragma unroll
        for (int j = 0; j < 8; ++j) f[j] = (__bf16)vr[c0 + j];
        a_wv[m0][s] = f;
      }
    }
  }
  __syncthreads();                      // ys staged

  // ---- phase 1: projections (wave owns p-block [32w, 32w+32)) ----
  f4 z4 = {0.f, 0.f, 0.f, 0.f};
  bf8 b_ys[2][2];
  #pragma unroll
  for (int nt = 0; nt < 2; ++nt) {
    int p = w*32 + nt*16 + l16;
    #pragma unroll
    for (int s = 0; s < 2; ++s)
      b_ys[nt][s] = *(const bf8*)&ys[p*YSTR + s*32 + quad*8];
  }
  #pragma unroll
  for (int nt = 0; nt < 2; ++nt) {
    int p = w*32 + nt*16 + l16;
    f4 aqk = z4;
    aqk = MFMA(a_qk[0], b_ys[nt][0], aqk);
    aqk = MFMA(a_qk[1], b_ys[nt][1], aqk);
    // C: row d = quad*4+reg (0..7 = q, 8..15 = k), col p
    __bf16* dp8 = ((quad < 2) ? qs : ks) + p*8 + (quad & 1)*4;
    #pragma unroll
    for (int rg = 0; rg < 4; ++rg) dp8[rg] = (__bf16)aqk[rg];
  }
  #pragma unroll
  for (int m0 = 0; m0 < 4; ++m0)
    #pragma unroll
    for (int nt = 0; nt < 2; ++nt) {
      f4 va = z4;
      va = MFMA(a_wv[m0][0], b_ys[nt][0], va);
      va = MFMA(a_wv[m0][1], b_ys[nt][1], va);
      int u = w*32 + nt*16 + l16;
      #pragma unroll
      for (int rg = 0; rg < 4; ++rg)
        vs[(m0*16 + quad*4 + rg)*VSTR + u] = (__bf16)va[rg];
    }
  __syncthreads();                      // qs/ks/vs visible

  // ---- phase 2: E = Q^T K (K=8 via quad-0 lanes, others zero) ----
  bf8 zb;
  #pragma unroll
  for (int j = 0; j < 8; ++j) zb[j] = (__bf16)0.f;
  f4 e[2][8];
  #pragma unroll
  for (int mt = 0; mt < 2; ++mt) {
    int p = w*32 + mt*16 + l16;
    bf8 aq = (quad == 0) ? *(const bf8*)&qs[p*8] : zb;
    #pragma unroll
    for (int nt = 0; nt < 8; ++nt) {
      bf8 bk = (quad == 0) ? *(const bf8*)&ks[(nt*16 + l16)*8] : zb;
      e[mt][nt] = MFMA(aq, bk, z4);
    }
  }
  __syncthreads();                      // qs/ks reads done (ps will clobber)

  // ---- phase 3: row softmax stats + P = exp(e - m) -> ps (bf16) ----
  int sb = (b*128 + r) << 7;
  #pragma unroll
  for (int mt = 0; mt < 2; ++mt) {
    if (dir) {                          // diag mask: c' == p
      #pragma unroll
      for (int nt = 0; nt < 8; ++nt)
        #pragma unroll
        for (int rg = 0; rg < 4; ++rg)
          if (nt == 2*w + mt && l16 == quad*4 + rg) e[mt][nt][rg] = NEGINF;
    }
    float mx[4], sm[4];
    #pragma unroll
    for (int rg = 0; rg < 4; ++rg) {
      float m2 = e[mt][0][rg];
      #pragma unroll
      for (int nt = 1; nt < 8; ++nt) m2 = fmaxf(m2, e[mt][nt][rg]);
      #pragma unroll
      for (int d2 = 1; d2 < 16; d2 <<= 1) m2 = fmaxf(m2, __shfl_xor(m2, d2, 64));
      mx[rg] = m2;
      sm[rg] = 0.f;
    }
    int prow = w*32 + mt*16 + quad*4;
    #pragma unroll
    for (int nt = 0; nt < 8; ++nt)
      #pragma unroll
      for (int rg = 0; rg < 4; ++rg) {
        float pv = __expf(e[mt][nt][rg] - mx[rg]);
        sm[rg] += pv;
        ps[(prow + rg)*PSTR + nt*16 + l16] = (__bf16)pv;
      }
    #pragma unroll
    for (int rg = 0; rg < 4; ++rg) {
      float s2 = sm[rg];
      #pragma unroll
      for (int d2 = 1; d2 < 16; d2 <<= 1) s2 += __shfl_xor(s2, d2, 64);
      if (l16 == 0) {
        mo[sb + prow + rg] = mx[rg];
        so[sb + prow + rg] = s2;
      }
    }
  }
  __syncthreads();                      // ps visible

  // ---- phase 4: O = V x P^T  (M=64 d, N=32 p per wave, K=128) ----
  f4 acc[4][2];
  #pragma unroll
  for (int m0 = 0; m0 < 4; ++m0)
    #pragma unroll
    for (int nt = 0; nt < 2; ++nt) acc[m0][nt] = z4;
  #pragma unroll
  for (int s = 0; s < 4; ++s) {
    bf8 af[4], bfr[2];
    #pragma unroll
    for (int m0 = 0; m0 < 4; ++m0)
      af[m0] = *(const bf8*)&vs[(m0*16 + l16)*VSTR + s*32 + quad*8];
    #pragma unroll
    for (int nt = 0; nt < 2; ++nt)
      bfr[nt] = *(const bf8*)&ps[(w*32 + nt*16 + l16)*PSTR + s*32 + quad*8];
    #pragma unroll
    for (int m0 = 0; m0 < 4; ++m0)
      #pragma unroll
      for (int nt = 0; nt < 2; ++nt)
        acc[m0][nt] = MFMA(af[m0], bfr[nt], acc[m0][nt]);
  }

  // ---- phase 5: stage fp32 out in own ps-row block, coalesced store ----
  float* oS = (float*)(smem + 17408 + 8704*w);   // [64][33] fp32, wave-local
  #pragma unroll
  for (int m0 = 0; m0 < 4; ++m0)
    #pragma unroll
    for (int nt = 0; nt < 2; ++nt)
      #pragma unroll
      for (int rg = 0; rg < 4; ++rg)
        oS[(m0*16 + quad*4 + rg)*33 + nt*16 + l16] = acc[m0][nt][rg];
  float* dp = dst + (size_t)b*1048576 + (size_t)r*128 + w*32;
  for (int i = lane; i < 2048; i += 64) {
    int d = i >> 5, pp = i & 31;
    dp[(size_t)d*16384 + pp] = oS[d*33 + pp];
  }
}

// Merge row stats (b,h,w) and col stats (b,w,h) -> per-pixel factors
// cW,cH at (b,h,w):  M=max, S=sW e^{mW-M} + sH e^{mH-M}, c* = e^{m*-M}/S.
__global__ __launch_bounds__(256) void scale_kernel(
    const float* __restrict__ mW, const float* __restrict__ sW,
    const float* __restrict__ mH, const float* __restrict__ sH,
    float* __restrict__ cW, float* __restrict__ cH) {
  __shared__ float tm[32][33], ts[32][33];
  int b = blockIdx.z;
  int x0 = blockIdx.x*32, y0 = blockIdx.y*32;
  const float* mh = mH + b*16384;
  const float* sh = sH + b*16384;
  for (int i = threadIdx.y; i < 32; i += 8) {
    tm[i][threadIdx.x] = mh[(y0 + i)*128 + x0 + threadIdx.x];
    ts[i][threadIdx.x] = sh[(y0 + i)*128 + x0 + threadIdx.x];
  }
  __syncthreads();
  for (int i = threadIdx.y; i < 32; i += 8) {
    int h = x0 + i, w2 = y0 + threadIdx.x;
    int idx = b*16384 + h*128 + w2;
    float mw = mW[idx], sw = sW[idx];
    float mhv = tm[threadIdx.x][i], shv = ts[threadIdx.x][i];
    float M = fmaxf(mw, mhv);
    float ew = __expf(mw - M), eh = __expf(mhv - M);
    float inv = 1.0f / (sw*ew + shv*eh);
    cW[idx] = ew*inv;
    cH[idx] = eh*inv;
  }
}

// Bo[b,d,h,w] = gamma*(Bo*cW + oT[b,d,w,h]*cH) + A[b,d,h,w].
__global__ __launch_bounds__(256) void combineT_kernel(
    float* __restrict__ Bo, const float* __restrict__ oT,
    const float* __restrict__ A, const float* __restrict__ cW,
    const float* __restrict__ cH, const float* __restrict__ gamma) {
  __shared__ float tile[32][33];
  int n = blockIdx.z;                       // b*64 + d
  int b = n >> 6;
  int x0 = blockIdx.x*32, y0 = blockIdx.y*32;
  const float* ip = oT + (size_t)n*16384;
  for (int i = threadIdx.y; i < 32; i += 8)
    tile[i][threadIdx.x] = ip[(size_t)(y0 + i)*128 + x0 + threadIdx.x];
  __syncthreads();
  float g = *gamma;
  for (int i = threadIdx.y; i < 32; i += 8) {
    int h = x0 + i, w2 = y0 + threadIdx.x;
    size_t idx = (size_t)n*16384 + (size_t)h*128 + w2;
    int pix = b*16384 + h*128 + w2;
    float oh = tile[threadIdx.x][i];
    Bo[idx] = g*(Bo[idx]*cW[pix] + oh*cH[pix]) + A[idx];
  }
}

// Pointwise 64->64 per (b,h) row.
__global__ __launch_bounds__(128) void pw_kernel(
    const float* __restrict__ A, const float* __restrict__ wpw, float* __restrict__ out) {
  __shared__ float ys[64][128];
  int w = threadIdx.x, h = blockIdx.x, b = blockIdx.y;
  for (int c = 0; c < 64; ++c)
    ys[c][w] = A[(((size_t)b*64 + c)*128 + h)*128 + w];
  __syncthreads();
  float acc[64] = {};
  for (int c0 = 0; c0 < 64; c0 += 8) {
    float yreg[8];
    #pragma unroll
    for (int cc = 0; cc < 8; ++cc) yreg[cc] = ys[c0 + cc][w];
    #pragma unroll
    for (int cc = 0; cc < 8; ++cc) {
      #pragma unroll
      for (int o = 0; o < 64; ++o)
        acc[o] += wpw[o*64 + c0 + cc] * yreg[cc];
    }
  }
  #pragma unroll
  for (int o = 0; o < 64; ++o)
    out[(((size_t)b*64 + o)*128 + h)*128 + w] = acc[o];
}

extern "C" void kernel_launch(void* const* d_in, const int* in_sizes, int n_in,
                              void* d_out, int out_size, void* d_ws, size_t ws_size,
                              hipStream_t stream) {
  const float* x     = (const float*)d_in[0];
  const float* wdw   = (const float*)d_in[1];
  const float* wq    = (const float*)d_in[2];
  const float* wk    = (const float*)d_in[3];
  const float* wv    = (const float*)d_in[4];
  const float* gamma = (const float*)d_in[5];
  const float* wpw   = (const float*)d_in[6];
  float* out = (float*)d_out;

  // Workspace (floats): 3*8388608 + 6*131072 = 25,952,256 (99 MB)
  float* ws = (float*)d_ws;
  float* y  = ws;                 // dwconv out / CCA1 in / CCA2 out
  float* z  = y  + 8388608;       // CCA1 out / CCA2 in
  float* AT = z  + 8388608;       // transposed input, then OH^T (in-place)
  float* mW = AT + 8388608;
  float* sW = mW + 131072;
  float* mH = sW + 131072;
  float* sH = mH + 131072;
  float* cW = sH + 131072;
  float* cH = cW + 131072;
  size_t need = (size_t)25952256 * sizeof(float);
  if (ws_size < need) return;

  dwconv_kernel<<<dim3(128, 64, 8), 128, 0, stream>>>(x, wdw, y);

  for (int pass = 0; pass < 2; ++pass) {
    const float* A = pass ? z : y;   // CCA input / residual
    float* Bo      = pass ? y : z;   // CCA output

    transpose128<<<dim3(4, 4, 512), dim3(32, 8), 0, stream>>>(A, AT);
    ccdir_kernel<<<dim3(128, 8, 2), 256, 0, stream>>>(
        A, Bo, AT, wq, wk, wv, mW, sW, mH, sH);
    scale_kernel<<<dim3(4, 4, 8), dim3(32, 8), 0, stream>>>(mW, sW, mH, sH, cW, cH);
    combineT_kernel<<<dim3(4, 4, 512), dim3(32, 8), 0, stream>>>(Bo, AT, A, cW, cH, gamma);
  }

  pw_kernel<<<dim3(128, 8), 128, 0, stream>>>(y, wpw, out);
}

// Round 4
// 277.679 us; speedup vs baseline: 3.3398x; 1.3725x over previous
//
#include <hip/hip_runtime.h>

// B=8, C=64, D=8 (q/k), H=W=128.  dwconv3x3 -> CCA -> CCA -> pointwise.
// MFMA flash CCA (ccdir); transposes fused into producers:
//   dwconv writes y and yT (tile kernel); combineT writes Bo and BoT (into AT).
// pw is MFMA (bf16 inputs, fp32 accum/out).
// Fragment layouts (mfma_f32_16x16x32_bf16):
//   A[m=lane&15][k=quad*8+j (+32s)], B[k][n=lane&15], C col=lane&15,row=quad*4+reg

#define NEGINF -3.0e38f
#define YSTR 72
#define VSTR 136
#define PSTR 136

typedef __attribute__((ext_vector_type(8))) __bf16 bf8;
typedef __attribute__((ext_vector_type(4))) float f4;

__device__ __forceinline__ f4 MFMA(bf8 a, bf8 b, f4 c) {
  return __builtin_amdgcn_mfma_f32_16x16x32_bf16(a, b, c, 0, 0, 0);
}

// 32x32-tile dwconv3x3; writes y and yT, both coalesced.
__global__ __launch_bounds__(256) void dwconv_kernel(
    const float* __restrict__ x, const float* __restrict__ wdw,
    float* __restrict__ y, float* __restrict__ yT) {
  __shared__ float in[34][36];
  __shared__ float ot[32][33];
  int tx = threadIdx.x & 31, ty = threadIdx.x >> 5;   // 32x8
  int w0 = blockIdx.x*32, h0 = blockIdx.y*32;
  int n = blockIdx.z;                                  // b*64 + c
  const float* xp = x + (size_t)n*16384;
  const float* wp = wdw + (n & 63)*9;
  float wr[9];
  #pragma unroll
  for (int j = 0; j < 9; ++j) wr[j] = wp[j];
  for (int i = ty; i < 34; i += 8) {
    int hh = h0 + i - 1;
    for (int j = tx; j < 34; j += 32) {
      int ww = w0 + j - 1;
      float v = 0.f;
      if (hh >= 0 && hh < 128 && ww >= 0 && ww < 128) v = xp[hh*128 + ww];
      in[i][j] = v;
    }
  }
  __syncthreads();
  for (int i2 = ty; i2 < 32; i2 += 8) {
    float acc = 0.f;
    #pragma unroll
    for (int kh = 0; kh < 3; ++kh)
      #pragma unroll
      for (int kw = 0; kw < 3; ++kw)
        acc += wr[kh*3 + kw]*in[i2 + kh][tx + kw];
    ot[i2][tx] = acc;
    y[(size_t)n*16384 + (size_t)(h0 + i2)*128 + w0 + tx] = acc;
  }
  __syncthreads();
  for (int i = ty; i < 32; i += 8)
    yT[(size_t)n*16384 + (size_t)(w0 + i)*128 + h0 + tx] = ot[tx][i];
}

// Fused CCA direction kernel. dir=0: src=A row pass -> dstRow, stats mW,sW.
// dir=1: src=dst=AT (in place), diag mask, stats mH,sH.
// Output O is UNNORMALIZED: O[d][p] = sum_c exp(e(p,c)-m[p]) * v[d][c].
__global__ __launch_bounds__(256) void ccdir_kernel(
    const float* __restrict__ srcRow, float* __restrict__ dstRow,
    float* __restrict__ srcdstCol,
    const float* __restrict__ wq, const float* __restrict__ wk,
    const float* __restrict__ wv,
    float* __restrict__ mW, float* __restrict__ sW,
    float* __restrict__ mH, float* __restrict__ sH) {
  // LDS: vs [64][136]bf16 @0; ps [128][136]bf16 @17408 (aliases ys and the
  // per-wave fp32 out-stage); qs @35840; ks @37888. Total 52224 B.
  __shared__ __align__(16) char smem[52224];
  __bf16* vs = (__bf16*)smem;
  __bf16* ps = (__bf16*)(smem + 17408);
  __bf16* ys = (__bf16*)(smem + 17408);
  __bf16* qs = (__bf16*)(smem + 35840);
  __bf16* ks = (__bf16*)(smem + 37888);

  int t = threadIdx.x;
  int r = blockIdx.x, b = blockIdx.y, dir = blockIdx.z;
  const float* src = dir ? srcdstCol : srcRow;
  float* dst       = dir ? srcdstCol : dstRow;
  float* mo        = dir ? mH : mW;
  float* so        = dir ? sH : sW;
  const float* sp = src + (size_t)b*1048576 + (size_t)r*128;

  // ---- phase 0: stage Y[c][p] -> ys[p][c] bf16; load weight A-frags ----
  for (int i = t; i < 8192; i += 256) {
    int c = i >> 7, p = i & 127;
    ys[p*YSTR + c] = (__bf16)sp[(size_t)c*16384 + p];
  }
  int lane = t & 63, w = t >> 6;
  int l16 = lane & 15, quad = lane >> 4;

  bf8 a_qk[2], a_wv[4][2];
  {
    const float* wr = (l16 < 8) ? (wq + l16*64) : (wk + (l16 - 8)*64);
    #pragma unroll
    for (int s = 0; s < 2; ++s) {
      int c0 = quad*8 + s*32;
      bf8 f;
      #pragma unroll
      for (int j = 0; j < 8; ++j) f[j] = (__bf16)wr[c0 + j];
      a_qk[s] = f;
    }
    #pragma unroll
    for (int m0 = 0; m0 < 4; ++m0) {
      const float* vr = wv + (m0*16 + l16)*64;
      #pragma unroll
      for (int s = 0; s < 2; ++s) {
        int c0 = quad*8 + s*32;
        bf8 f;
        #pragma unroll
        for (int j = 0; j < 8; ++j) f[j] = (__bf16)vr[c0 + j];
        a_wv[m0][s] = f;
      }
    }
  }
  __syncthreads();                      // ys staged

  // ---- phase 1: projections (wave owns p-block [32w, 32w+32)) ----
  f4 z4 = {0.f, 0.f, 0.f, 0.f};
  bf8 b_ys[2][2];
  #pragma unroll
  for (int nt = 0; nt < 2; ++nt) {
    int p = w*32 + nt*16 + l16;
    #pragma unroll
    for (int s = 0; s < 2; ++s)
      b_ys[nt][s] = *(const bf8*)&ys[p*YSTR + s*32 + quad*8];
  }
  #pragma unroll
  for (int nt = 0; nt < 2; ++nt) {
    int p = w*32 + nt*16 + l16;
    f4 aqk = z4;
    aqk = MFMA(a_qk[0], b_ys[nt][0], aqk);
    aqk = MFMA(a_qk[1], b_ys[nt][1], aqk);
    __bf16* dp8 = ((quad < 2) ? qs : ks) + p*8 + (quad & 1)*4;
    #pragma unroll
    for (int rg = 0; rg < 4; ++rg) dp8[rg] = (__bf16)aqk[rg];
  }
  #pragma unroll
  for (int m0 = 0; m0 < 4; ++m0)
    #pragma unroll
    for (int nt = 0; nt < 2; ++nt) {
      f4 va = z4;
      va = MFMA(a_wv[m0][0], b_ys[nt][0], va);
      va = MFMA(a_wv[m0][1], b_ys[nt][1], va);
      int u = w*32 + nt*16 + l16;
      #pragma unroll
      for (int rg = 0; rg < 4; ++rg)
        vs[(m0*16 + quad*4 + rg)*VSTR + u] = (__bf16)va[rg];
    }
  __syncthreads();                      // qs/ks/vs visible

  // ---- phase 2: E = Q^T K (K=8 via quad-0 lanes, others zero) ----
  bf8 zb;
  #pragma unroll
  for (int j = 0; j < 8; ++j) zb[j] = (__bf16)0.f;
  f4 e[2][8];
  #pragma unroll
  for (int mt = 0; mt < 2; ++mt) {
    int p = w*32 + mt*16 + l16;
    bf8 aq = (quad == 0) ? *(const bf8*)&qs[p*8] : zb;
    #pragma unroll
    for (int nt = 0; nt < 8; ++nt) {
      bf8 bk = (quad == 0) ? *(const bf8*)&ks[(nt*16 + l16)*8] : zb;
      e[mt][nt] = MFMA(aq, bk, z4);
    }
  }
  __syncthreads();                      // qs/ks reads done (ps will clobber)

  // ---- phase 3: row softmax stats + P = exp(e - m) -> ps (bf16) ----
  int sb = (b*128 + r) << 7;
  #pragma unroll
  for (int mt = 0; mt < 2; ++mt) {
    if (dir) {                          // diag mask: c' == p
      #pragma unroll
      for (int nt = 0; nt < 8; ++nt)
        #pragma unroll
        for (int rg = 0; rg < 4; ++rg)
          if (nt == 2*w + mt && l16 == quad*4 + rg) e[mt][nt][rg] = NEGINF;
    }
    float mx[4], sm[4];
    #pragma unroll
    for (int rg = 0; rg < 4; ++rg) {
      float m2 = e[mt][0][rg];
      #pragma unroll
      for (int nt = 1; nt < 8; ++nt) m2 = fmaxf(m2, e[mt][nt][rg]);
      #pragma unroll
      for (int d2 = 1; d2 < 16; d2 <<= 1) m2 = fmaxf(m2, __shfl_xor(m2, d2, 64));
      mx[rg] = m2;
      sm[rg] = 0.f;
    }
    int prow = w*32 + mt*16 + quad*4;
    #pragma unroll
    for (int nt = 0; nt < 8; ++nt)
      #pragma unroll
      for (int rg = 0; rg < 4; ++rg) {
        float pv = __expf(e[mt][nt][rg] - mx[rg]);
        sm[rg] += pv;
        ps[(prow + rg)*PSTR + nt*16 + l16] = (__bf16)pv;
      }
    #pragma unroll
    for (int rg = 0; rg < 4; ++rg) {
      float s2 = sm[rg];
      #pragma unroll
      for (int d2 = 1; d2 < 16; d2 <<= 1) s2 += __shfl_xor(s2, d2, 64);
      if (l16 == 0) {
        mo[sb + prow + rg] = mx[rg];
        so[sb + prow + rg] = s2;
      }
    }
  }
  __syncthreads();                      // ps visible

  // ---- phase 4: O = V x P^T  (M=64 d, N=32 p per wave, K=128) ----
  f4 acc[4][2];
  #pragma unroll
  for (int m0 = 0; m0 < 4; ++m0)
    #pragma unroll
    for (int nt = 0; nt < 2; ++nt) acc[m0][nt] = z4;
  #pragma unroll
  for (int s = 0; s < 4; ++s) {
    bf8 af[4], bfr[2];
    #pragma unroll
    for (int m0 = 0; m0 < 4; ++m0)
      af[m0] = *(const bf8*)&vs[(m0*16 + l16)*VSTR + s*32 + quad*8];
    #pragma unroll
    for (int nt = 0; nt < 2; ++nt)
      bfr[nt] = *(const bf8*)&ps[(w*32 + nt*16 + l16)*PSTR + s*32 + quad*8];
    #pragma unroll
    for (int m0 = 0; m0 < 4; ++m0)
      #pragma unroll
      for (int nt = 0; nt < 2; ++nt)
        acc[m0][nt] = MFMA(af[m0], bfr[nt], acc[m0][nt]);
  }

  // ---- phase 5: stage fp32 out in own ps-row block, coalesced store ----
  float* oS = (float*)(smem + 17408 + 8704*w);   // [64][33] fp32, wave-local
  #pragma unroll
  for (int m0 = 0; m0 < 4; ++m0)
    #pragma unroll
    for (int nt = 0; nt < 2; ++nt)
      #pragma unroll
      for (int rg = 0; rg < 4; ++rg)
        oS[(m0*16 + quad*4 + rg)*33 + nt*16 + l16] = acc[m0][nt][rg];
  float* dp = dst + (size_t)b*1048576 + (size_t)r*128 + w*32;
  for (int i = lane; i < 2048; i += 64) {
    int d = i >> 5, pp = i & 31;
    dp[(size_t)d*16384 + pp] = oS[d*33 + pp];
  }
}

// Merge row stats (b,h,w) and col stats (b,w,h) -> per-pixel factors cW,cH.
__global__ __launch_bounds__(256) void scale_kernel(
    const float* __restrict__ mW, const float* __restrict__ sW,
    const float* __restrict__ mH, const float* __restrict__ sH,
    float* __restrict__ cW, float* __restrict__ cH) {
  __shared__ float tm[32][33], ts[32][33];
  int b = blockIdx.z;
  int x0 = blockIdx.x*32, y0 = blockIdx.y*32;
  const float* mh = mH + b*16384;
  const float* sh = sH + b*16384;
  for (int i = threadIdx.y; i < 32; i += 8) {
    tm[i][threadIdx.x] = mh[(y0 + i)*128 + x0 + threadIdx.x];
    ts[i][threadIdx.x] = sh[(y0 + i)*128 + x0 + threadIdx.x];
  }
  __syncthreads();
  for (int i = threadIdx.y; i < 32; i += 8) {
    int h = x0 + i, w2 = y0 + threadIdx.x;
    int idx = b*16384 + h*128 + w2;
    float mw = mW[idx], sw = sW[idx];
    float mhv = tm[threadIdx.x][i], shv = ts[threadIdx.x][i];
    float M = fmaxf(mw, mhv);
    float ew = __expf(mw - M), eh = __expf(mhv - M);
    float inv = 1.0f / (sw*ew + shv*eh);
    cW[idx] = ew*inv;
    cH[idx] = eh*inv;
  }
}

// Bo = gamma*(Bo*cW + oT^T*cH) + A; optionally also write Bo^T into BoT.
// BoT may alias oT (tile is read into LDS before the overwrite).
__global__ __launch_bounds__(256) void combineT_kernel(
    float* __restrict__ Bo, const float* oT,
    const float* __restrict__ A, const float* __restrict__ cW,
    const float* __restrict__ cH, const float* __restrict__ gamma,
    float* BoT, int writeT) {
  __shared__ float tile[32][33];
  __shared__ float rt[32][33];
  int n = blockIdx.z;                       // b*64 + d
  int b = n >> 6;
  int x0 = blockIdx.x*32, y0 = blockIdx.y*32;
  const float* ip = oT + (size_t)n*16384;
  for (int i = threadIdx.y; i < 32; i += 8)
    tile[i][threadIdx.x] = ip[(size_t)(y0 + i)*128 + x0 + threadIdx.x];
  __syncthreads();
  float g = *gamma;
  for (int i = threadIdx.y; i < 32; i += 8) {
    int h = x0 + i, w2 = y0 + threadIdx.x;
    size_t idx = (size_t)n*16384 + (size_t)h*128 + w2;
    int pix = b*16384 + h*128 + w2;
    float res = g*(Bo[idx]*cW[pix] + tile[threadIdx.x][i]*cH[pix]) + A[idx];
    Bo[idx] = res;
    rt[i][threadIdx.x] = res;               // value at (h=x0+i, w=y0+tx)
  }
  if (writeT) {
    __syncthreads();
    for (int i = threadIdx.y; i < 32; i += 8)
      BoT[(size_t)n*16384 + (size_t)(y0 + i)*128 + x0 + threadIdx.x] =
          rt[threadIdx.x][i];
  }
}

// MFMA pointwise 64->64 per (b,r) slice: out[o][p] = sum_c wpw[o][c]*A[c][p].
__global__ __launch_bounds__(256) void pw_kernel(
    const float* __restrict__ A, const float* __restrict__ wpw,
    float* __restrict__ out) {
  __shared__ __align__(16) char smem[52224];  // ys 18432 + 4x8448 out-stage
  __bf16* ys = (__bf16*)smem;                 // [128][72]
  int t = threadIdx.x;
  int r = blockIdx.x, b = blockIdx.y;
  const float* sp = A + (size_t)b*1048576 + (size_t)r*128;
  for (int i = t; i < 8192; i += 256) {
    int c = i >> 7, p = i & 127;
    ys[p*YSTR + c] = (__bf16)sp[(size_t)c*16384 + p];
  }
  int lane = t & 63, w = t >> 6;
  int l16 = lane & 15, quad = lane >> 4;
  bf8 a_w[4][2];
  #pragma unroll
  for (int m0 = 0; m0 < 4; ++m0) {
    const float* wr = wpw + (m0*16 + l16)*64;
    #pragma unroll
    for (int s = 0; s < 2; ++s) {
      bf8 f;
      #pragma unroll
      for (int j = 0; j < 8; ++j) f[j] = (__bf16)wr[quad*8 + s*32 + j];
      a_w[m0][s] = f;
    }
  }
  __syncthreads();
  f4 z4 = {0.f, 0.f, 0.f, 0.f};
  bf8 b_ys[2][2];
  #pragma unroll
  for (int nt = 0; nt < 2; ++nt) {
    int p = w*32 + nt*16 + l16;
    #pragma unroll
    for (int s = 0; s < 2; ++s)
      b_ys[nt][s] = *(const bf8*)&ys[p*YSTR + s*32 + quad*8];
  }
  f4 acc[4][2];
  #pragma unroll
  for (int m0 = 0; m0 < 4; ++m0)
    #pragma unroll
    for (int nt = 0; nt < 2; ++nt) {
      f4 a2 = z4;
      a2 = MFMA(a_w[m0][0], b_ys[nt][0], a2);
      a2 = MFMA(a_w[m0][1], b_ys[nt][1], a2);
      acc[m0][nt] = a2;
    }
  float* oS = (float*)(smem + 18432 + 8448*w);  // [64][33] fp32, wave-local
  #pragma unroll
  for (int m0 = 0; m0 < 4; ++m0)
    #pragma unroll
    for (int nt = 0; nt < 2; ++nt)
      #pragma unroll
      for (int rg = 0; rg < 4; ++rg)
        oS[(m0*16 + quad*4 + rg)*33 + nt*16 + l16] = acc[m0][nt][rg];
  float* dp = out + (size_t)b*1048576 + (size_t)r*128 + w*32;
  for (int i = lane; i < 2048; i += 64) {
    int d = i >> 5, pp = i & 31;
    dp[(size_t)d*16384 + pp] = oS[d*33 + pp];
  }
}

extern "C" void kernel_launch(void* const* d_in, const int* in_sizes, int n_in,
                              void* d_out, int out_size, void* d_ws, size_t ws_size,
                              hipStream_t stream) {
  const float* x     = (const float*)d_in[0];
  const float* wdw   = (const float*)d_in[1];
  const float* wq    = (const float*)d_in[2];
  const float* wk    = (const float*)d_in[3];
  const float* wv    = (const float*)d_in[4];
  const float* gamma = (const float*)d_in[5];
  const float* wpw   = (const float*)d_in[6];
  float* out = (float*)d_out;

  // Workspace (floats): 3*8388608 + 6*131072 = 25,952,256 (99 MB)
  float* ws = (float*)d_ws;
  float* y  = ws;                 // dwconv out / CCA1 in / CCA2 out
  float* z  = y  + 8388608;       // CCA1 out / CCA2 in
  float* AT = z  + 8388608;       // transposed input, then OH^T (in-place)
  float* mW = AT + 8388608;
  float* sW = mW + 131072;
  float* mH = sW + 131072;
  float* sH = mH + 131072;
  float* cW = sH + 131072;
  float* cH = cW + 131072;
  size_t need = (size_t)25952256 * sizeof(float);
  if (ws_size < need) return;

  dwconv_kernel<<<dim3(4, 4, 512), 256, 0, stream>>>(x, wdw, y, AT);

  for (int pass = 0; pass < 2; ++pass) {
    const float* A = pass ? z : y;   // CCA input / residual
    float* Bo      = pass ? y : z;   // CCA output

    ccdir_kernel<<<dim3(128, 8, 2), 256, 0, stream>>>(
        A, Bo, AT, wq, wk, wv, mW, sW, mH, sH);
    scale_kernel<<<dim3(4, 4, 8), dim3(32, 8), 0, stream>>>(mW, sW, mH, sH, cW, cH);
    // pass 0: also write Bo^T into AT (becomes next pass's transposed input)
    combineT_kernel<<<dim3(4, 4, 512), dim3(32, 8), 0, stream>>>(
        Bo, AT, A, cW, cH, gamma, AT, pass == 0 ? 1 : 0);
  }

  pw_kernel<<<dim3(128, 8), 256, 0, stream>>>(y, wpw, out);
}